// Round 29
// baseline (29.454 us; speedup 1.0000x reference)
//
#include <hip/hip_runtime.h>

// RNNFFT: depth-10 radix-2 butterfly network over last dim (1024).
// v = x; for l = 9..0: y = B_l(w_l * v); v = (l==1) ? y : x + y
// Pairs at level l: (e, e^h), h = 512>>l. Twiddle: bw[OFF[l] + (e & (n_l-1))].
// Mix (lw^T): role-j: y = lw[j][j]*t_self + lw[1-j][j]*t_partner.
//
// Structure = r28 (best, 28.5us): 256-thr blocks, two-layout butterfly,
// shared per-wave 4KB xr/v A->B buffer, bw staged in LDS, fma-fused residual,
// nt stores. LDS 24KB -> 6 blocks/CU. Equilibrium: VALU 9.4us / DS ~54% /
// HBM ~53% - latency-bound, no pipe saturated.
// This round, three micro-cuts (zero structural risk):
//  1. level 9 reads xr directly (kills the v=xr copy, 16 movs);
//  2. level-9 coefficient prefusion c=lw*w (n=2 only level where it nets
//     positive: 2mul+4fma -> 4fma per pair, -12 ops);
//  3. loadw_B<1>/<0> hoisted before level_B<3> - all B-twiddle DS reads
//     queue behind the vB read, drain under compute (+24 transient VGPR,
//     peak ~70 <= 84 -> still 6 waves/SIMD).
// absmax expected ~0.01-0.03 (level-9 re-association), threshold 0.109.

constexpr int VECLEN = 1024;

__device__ __forceinline__ int swz(int f) {      // XOR bits[4:2] with bits[7:5]
  return f ^ (((f >> 5) & 7) << 2);              // preserves 16B groups
}

// Level 9 (first level): reads xr directly, prefused coefficients.
__device__ __forceinline__ void level9_first(float (&v)[16], const float (&xr)[16],
                                             const float* __restrict__ bw,
                                             const float* __restrict__ lw) {
  const float w0 = bw[2046], w1 = bw[2047];      // OFFSETS[9], n=2
  const float c00 = lw[36]*w0, c01 = lw[37]*w0;  // lw[9] = lw + 36
  const float c10 = lw[38]*w1, c11 = lw[39]*w1;
#pragma unroll
  for (int r = 0; r < 16; r += 2) {
    const int q = r + 1;
    v[r] = __builtin_fmaf(c00, xr[r], __builtin_fmaf(c10, xr[q], xr[r]));  // role 0
    v[q] = __builtin_fmaf(c11, xr[q], __builtin_fmaf(c01, xr[r], xr[q]));  // role 1
  }
}

template<int L, bool RESL>
__device__ __forceinline__ void level_inlane(float (&v)[16], const float (&xr)[16],
                                             const float* __restrict__ bw,
                                             const float* __restrict__ lw) {
  constexpr int n = VECLEN >> L;          // 8, 4 (levels 8..7..6 use 4,8,16)
  constexpr int h = n >> 1;
  constexpr int off = 2048 - (2048 >> L); // OFFSETS[L]
  float w[n];                              // lane-uniform -> scalar loads
#pragma unroll
  for (int i = 0; i < n; ++i) w[i] = bw[off + i];
  const float l00 = lw[L*4+0], l01 = lw[L*4+1], l10 = lw[L*4+2], l11 = lw[L*4+3];
#pragma unroll
  for (int r = 0; r < 16; ++r) {
    if ((r & h) == 0) {
      const int q = r ^ h;
      const float t0 = w[r & (n-1)] * v[r];
      const float t1 = w[q & (n-1)] * v[q];
      if (RESL) {
        v[r] = __builtin_fmaf(l00, t0, __builtin_fmaf(l10, t1, xr[r]));  // role 0
        v[q] = __builtin_fmaf(l11, t1, __builtin_fmaf(l01, t0, xr[q]));  // role 1
      } else {
        v[r] = __builtin_fmaf(l00, t0, l10*t1);
        v[q] = __builtin_fmaf(l11, t1, l01*t0);
      }
    }
  }
}

template<int L, bool RESL>
__device__ __forceinline__ void level_dpp(float (&v)[16], const float (&xr)[16],
                                          const float (&w)[16],
                                          const float* __restrict__ lw, int lane) {
  static_assert(L == 4 || L == 5, "DPP levels only");
  constexpr int ctl = (L == 5) ? 0xB1 : 0x4E;
  const int role = (lane >> (5 - L)) & 1;
  const float l00 = lw[L*4+0], l01 = lw[L*4+1], l10 = lw[L*4+2], l11 = lw[L*4+3];
  const float cs = role ? l11 : l00;      // coeff on own t
  const float cp = role ? l01 : l10;      // coeff on partner t
#pragma unroll
  for (int r = 0; r < 16; ++r) {
    const float t = w[r] * v[r];
    const float tp = __int_as_float(
        __builtin_amdgcn_update_dpp(0, __float_as_int(t), ctl, 0xF, 0xF, true));
    if (RESL) v[r] = __builtin_fmaf(cs, t, __builtin_fmaf(cp, tp, xr[r]));
    else      v[r] = __builtin_fmaf(cs, t, cp*tp);
  }
}

template<int L>
__device__ __forceinline__ void loadw_A(float (&w)[16], const float* lds_bw, int lane) {
  constexpr int n = VECLEN >> L;
  constexpr int off = 2048 - (2048 >> L);
  const int f0 = off + ((lane * 16) & (n - 1));
#pragma unroll
  for (int k = 0; k < 4; ++k) {
    const float4 f = *reinterpret_cast<const float4*>(lds_bw + swz(f0 + 4*k));
    w[4*k+0]=f.x; w[4*k+1]=f.y; w[4*k+2]=f.z; w[4*k+3]=f.w;
  }
}

template<int L>
__device__ __forceinline__ void loadw_B(float* w, const float* lds_bw, int lane) {
  constexpr int off = 2048 - (2048 >> L);
  constexpr int nr = (VECLEN >> L) >> 6;   // 16, 8, 4, 2
#pragma unroll
  for (int j = 0; j < nr; ++j)
    w[j] = lds_bw[swz(off + j*64 + lane)];
}

template<int L, bool RESL>
__device__ __forceinline__ void level_B(float (&v)[16], const float (&xr)[16],
                                        const float* w, const float* __restrict__ lw) {
  constexpr int nr = (VECLEN >> L) >> 6;   // 16, 8, 4, 2
  constexpr int hb = nr >> 1;              // 8, 4, 2, 1
  const float l00 = lw[L*4+0], l01 = lw[L*4+1], l10 = lw[L*4+2], l11 = lw[L*4+3];
#pragma unroll
  for (int r = 0; r < 16; ++r) {
    if ((r & hb) == 0) {
      const int q = r ^ hb;
      const float t0 = w[r & (nr-1)] * v[r];
      const float t1 = w[q & (nr-1)] * v[q];
      if (RESL) {
        v[r] = __builtin_fmaf(l00, t0, __builtin_fmaf(l10, t1, xr[r]));
        v[q] = __builtin_fmaf(l11, t1, __builtin_fmaf(l01, t0, xr[q]));
      } else {
        v[r] = __builtin_fmaf(l00, t0, l10*t1);
        v[q] = __builtin_fmaf(l11, t1, l01*t0);
      }
    }
  }
}

__global__ __launch_bounds__(256)
void rnnfft_kernel(const float* __restrict__ x,
                   const float* __restrict__ bw,
                   const float* __restrict__ lw,
                   float* __restrict__ out, int nvec) {
  __shared__ float lds_bw[2048];           // swizzled bw[0..2016)  (8 KB)
  __shared__ float tbuf[4][1024];          // per-wave SHARED xr/v buffer (16 KB)
  const int t = threadIdx.x;
  const int w4 = t >> 6;
  const int lane = t & 63;
  const int wid = blockIdx.x * 4 + w4;     // wave id = vector id (grid exact)
  const size_t base = (size_t)wid * VECLEN;
  float* buf = tbuf[w4];

  // x in layout A (the ONLY global read of x).
  float v[16], xr[16];
#pragma unroll
  for (int k = 0; k < 4; ++k) {
    const float4 f = *reinterpret_cast<const float4*>(x + base + lane*16 + 4*k);
    xr[4*k+0]=f.x; xr[4*k+1]=f.y; xr[4*k+2]=f.z; xr[4*k+3]=f.w;
  }

  // Stash xr into the shared per-wave buffer (first use of the buffer).
#pragma unroll
  for (int k = 0; k < 4; ++k) {
    float4 f;
    f.x = xr[4*k+0]; f.y = xr[4*k+1]; f.z = xr[4*k+2]; f.w = xr[4*k+3];
    *reinterpret_cast<float4*>(buf + swz(lane*16 + 4*k)) = f;
  }

  // Stage bw[0..2016) into LDS (swizzled), once per block.
  if (t < 252) {
    const float4 a = *reinterpret_cast<const float4*>(bw + 8*t);
    const float4 b = *reinterpret_cast<const float4*>(bw + 8*t + 4);
    *reinterpret_cast<float4*>(lds_bw + swz(8*t)) = a;
    *reinterpret_cast<float4*>(lds_bw + swz(8*t+4)) = b;
  }
  __syncthreads();

  // Prefetch DPP-level twiddles from LDS (land during in-lane levels).
  float wA[16], wB[16];
  loadw_A<5>(wA, lds_bw, lane);
  loadw_A<4>(wB, lds_bw, lane);

  // Layout A: level 9 reads xr directly (no v=xr copy); 8..6 in-lane;
  // 5 and 4 via DPP.
  level9_first(v, xr, bw, lw);
  level_inlane<8, true>(v, xr, bw, lw);
  level_inlane<7, true>(v, xr, bw, lw);
  level_inlane<6, true>(v, xr, bw, lw);
  level_dpp<5, true>(v, xr, wA, lw, lane);
  level_dpp<4, true>(v, xr, wB, lw, lane);

  // Read xr back in B layout BEFORE overwriting the buffer with v.
  float xrB[16];
#pragma unroll
  for (int r = 0; r < 16; ++r) xrB[r] = buf[swz(r*64 + lane)];

  // Transpose v: A -> B through the same buffer.
#pragma unroll
  for (int k = 0; k < 4; ++k) {
    float4 f;
    f.x = v[4*k+0]; f.y = v[4*k+1]; f.z = v[4*k+2]; f.w = v[4*k+3];
    *reinterpret_cast<float4*>(buf + swz(lane*16 + 4*k)) = f;
  }

  // ALL B-twiddle reads issued here: they queue behind the vB read on the
  // in-order DS pipe and drain under level_B<3>/<2> compute.
  float w3[2], w2[4], w1[8], w0[16];
  loadw_B<3>(w3, lds_bw, lane);
  loadw_B<2>(w2, lds_bw, lane);
  loadw_B<1>(w1, lds_bw, lane);
  loadw_B<0>(w0, lds_bw, lane);

#pragma unroll
  for (int r = 0; r < 16; ++r) v[r] = buf[swz(r*64 + lane)];

  // Layout B: levels 3..0 all in-lane (pure VALU).
  level_B<3, true >(v, xrB, w3, lw);
  level_B<2, true >(v, xrB, w2, lw);
  level_B<1, false>(v, xrB, w1, lw);   // RES[1] = False
  level_B<0, true >(v, xrB, w0, lw);

  // Nontemporal coalesced stores (r22 win: out stops polluting caches).
#pragma unroll
  for (int r = 0; r < 16; ++r)
    __builtin_nontemporal_store(v[r], &out[base + r*64 + lane]);
}

extern "C" void kernel_launch(void* const* d_in, const int* in_sizes, int n_in,
                              void* d_out, int out_size, void* d_ws, size_t ws_size,
                              hipStream_t stream) {
  const float* x  = (const float*)d_in[0];
  const float* bw = (const float*)d_in[1];
  const float* lw = (const float*)d_in[2];
  float* out = (float*)d_out;
  const int nvec = in_sizes[0] / VECLEN;        // 16384 vectors
  const int wpb = 4;                            // waves per block (256 threads)
  const int blocks = (nvec + wpb - 1) / wpb;    // 4096, exact
  rnnfft_kernel<<<blocks, 256, 0, stream>>>(x, bw, lw, out, nvec);
}

// Round 30
// 28.473 us; speedup vs baseline: 1.0345x; 1.0345x over previous
//
#include <hip/hip_runtime.h>

// RNNFFT: depth-10 radix-2 butterfly network over last dim (1024).
// v = x; for l = 9..0: y = B_l(w_l * v); v = (l==1) ? y : x + y
// Pairs at level l: (e, e^h), h = 512>>l. Twiddle: bw[OFF[l] + (e & (n_l-1))].
// Mix (lw^T): role-j: y = lw[j][j]*t_self + lw[1-j][j]*t_partner.
//
// FINAL = r28 (best, 28.5us), restored verbatim after r29's micro-cuts
// (hoisted B-twiddle loads, level-9 prefusion) regressed to 29.5 - in this
// latency-equilibrium regime, live-range/issue structure beats instruction
// count. Structure: 256-thr blocks; two-layout butterfly (A: levels 9..6
// in-lane + 5,4 DPP quad_perm; one per-wave XOR-swizzled LDS transpose;
// B: levels 3..0 in-lane); bw staged in LDS; shared per-wave 4KB xr/v A->B
// buffer (sequential lifetimes, in-order DS); fma-fused residual
// (r28: -25% level math, absmax 0.0156 << 0.109); nontemporal stores
// (r22: out stops evicting x from L3/L2). LDS 24KB -> 6 blocks/CU.
// Session ledger (29 rounds): occupancy r4/r19/r25 null; VALU r14 null /
// r28 real; latency r15/r27 null; DS-count r16/r18/r26 negative; VMEM
// r13/r20 null/negative; packing r12/r14 negative/null; nt stores +1us;
// LDS-budget composition (r24) +1us; fma fusion (r28) +1us.

constexpr int VECLEN = 1024;

__device__ __forceinline__ int swz(int f) {      // XOR bits[4:2] with bits[7:5]
  return f ^ (((f >> 5) & 7) << 2);              // preserves 16B groups
}

template<int L, bool RESL>
__device__ __forceinline__ void level_inlane(float (&v)[16], const float (&xr)[16],
                                             const float* __restrict__ bw,
                                             const float* __restrict__ lw) {
  constexpr int n = VECLEN >> L;          // 16, 8, 4, 2
  constexpr int h = n >> 1;               // 8, 4, 2, 1
  constexpr int off = 2048 - (2048 >> L); // OFFSETS[L]
  float w[n];                              // lane-uniform -> scalar loads
#pragma unroll
  for (int i = 0; i < n; ++i) w[i] = bw[off + i];
  const float l00 = lw[L*4+0], l01 = lw[L*4+1], l10 = lw[L*4+2], l11 = lw[L*4+3];
#pragma unroll
  for (int r = 0; r < 16; ++r) {
    if ((r & h) == 0) {
      const int q = r ^ h;
      const float t0 = w[r & (n-1)] * v[r];
      const float t1 = w[q & (n-1)] * v[q];
      if (RESL) {
        v[r] = __builtin_fmaf(l00, t0, __builtin_fmaf(l10, t1, xr[r]));  // role 0
        v[q] = __builtin_fmaf(l11, t1, __builtin_fmaf(l01, t0, xr[q]));  // role 1
      } else {
        v[r] = l00*t0 + l10*t1;
        v[q] = l01*t0 + l11*t1;
      }
    }
  }
}

template<int L, bool RESL>
__device__ __forceinline__ void level_dpp(float (&v)[16], const float (&xr)[16],
                                          const float (&w)[16],
                                          const float* __restrict__ lw, int lane) {
  static_assert(L == 4 || L == 5, "DPP levels only");
  constexpr int ctl = (L == 5) ? 0xB1 : 0x4E;
  const int role = (lane >> (5 - L)) & 1;
  const float l00 = lw[L*4+0], l01 = lw[L*4+1], l10 = lw[L*4+2], l11 = lw[L*4+3];
  const float cs = role ? l11 : l00;      // coeff on own t
  const float cp = role ? l01 : l10;      // coeff on partner t
#pragma unroll
  for (int r = 0; r < 16; ++r) {
    const float t = w[r] * v[r];
    const float tp = __int_as_float(
        __builtin_amdgcn_update_dpp(0, __float_as_int(t), ctl, 0xF, 0xF, true));
    if (RESL) v[r] = __builtin_fmaf(cs, t, __builtin_fmaf(cp, tp, xr[r]));
    else      v[r] = cs*t + cp*tp;
  }
}

template<int L>
__device__ __forceinline__ void loadw_A(float (&w)[16], const float* lds_bw, int lane) {
  constexpr int n = VECLEN >> L;
  constexpr int off = 2048 - (2048 >> L);
  const int f0 = off + ((lane * 16) & (n - 1));
#pragma unroll
  for (int k = 0; k < 4; ++k) {
    const float4 f = *reinterpret_cast<const float4*>(lds_bw + swz(f0 + 4*k));
    w[4*k+0]=f.x; w[4*k+1]=f.y; w[4*k+2]=f.z; w[4*k+3]=f.w;
  }
}

template<int L>
__device__ __forceinline__ void loadw_B(float* w, const float* lds_bw, int lane) {
  constexpr int off = 2048 - (2048 >> L);
  constexpr int nr = (VECLEN >> L) >> 6;   // 16, 8, 4, 2
#pragma unroll
  for (int j = 0; j < nr; ++j)
    w[j] = lds_bw[swz(off + j*64 + lane)];
}

template<int L, bool RESL>
__device__ __forceinline__ void level_B(float (&v)[16], const float (&xr)[16],
                                        const float* w, const float* __restrict__ lw) {
  constexpr int nr = (VECLEN >> L) >> 6;   // 16, 8, 4, 2
  constexpr int hb = nr >> 1;              // 8, 4, 2, 1
  const float l00 = lw[L*4+0], l01 = lw[L*4+1], l10 = lw[L*4+2], l11 = lw[L*4+3];
#pragma unroll
  for (int r = 0; r < 16; ++r) {
    if ((r & hb) == 0) {
      const int q = r ^ hb;
      const float t0 = w[r & (nr-1)] * v[r];
      const float t1 = w[q & (nr-1)] * v[q];
      if (RESL) {
        v[r] = __builtin_fmaf(l00, t0, __builtin_fmaf(l10, t1, xr[r]));
        v[q] = __builtin_fmaf(l11, t1, __builtin_fmaf(l01, t0, xr[q]));
      } else {
        v[r] = l00*t0 + l10*t1;
        v[q] = l01*t0 + l11*t1;
      }
    }
  }
}

__global__ __launch_bounds__(256)
void rnnfft_kernel(const float* __restrict__ x,
                   const float* __restrict__ bw,
                   const float* __restrict__ lw,
                   float* __restrict__ out, int nvec) {
  __shared__ float lds_bw[2048];           // swizzled bw[0..2016)  (8 KB)
  __shared__ float tbuf[4][1024];          // per-wave SHARED xr/v buffer (16 KB)
  const int t = threadIdx.x;
  const int w4 = t >> 6;
  const int lane = t & 63;
  const int wid = blockIdx.x * 4 + w4;     // wave id = vector id (grid exact)
  const size_t base = (size_t)wid * VECLEN;
  float* buf = tbuf[w4];

  // x in layout A (the ONLY global read of x).
  float v[16], xr[16];
#pragma unroll
  for (int k = 0; k < 4; ++k) {
    const float4 f = *reinterpret_cast<const float4*>(x + base + lane*16 + 4*k);
    xr[4*k+0]=f.x; xr[4*k+1]=f.y; xr[4*k+2]=f.z; xr[4*k+3]=f.w;
  }

  // Stash xr into the shared per-wave buffer (first use of the buffer).
#pragma unroll
  for (int k = 0; k < 4; ++k) {
    float4 f;
    f.x = xr[4*k+0]; f.y = xr[4*k+1]; f.z = xr[4*k+2]; f.w = xr[4*k+3];
    *reinterpret_cast<float4*>(buf + swz(lane*16 + 4*k)) = f;
  }

  // Stage bw[0..2016) into LDS (swizzled), once per block.
  if (t < 252) {
    const float4 a = *reinterpret_cast<const float4*>(bw + 8*t);
    const float4 b = *reinterpret_cast<const float4*>(bw + 8*t + 4);
    *reinterpret_cast<float4*>(lds_bw + swz(8*t)) = a;
    *reinterpret_cast<float4*>(lds_bw + swz(8*t+4)) = b;
  }
  __syncthreads();

#pragma unroll
  for (int r = 0; r < 16; ++r) v[r] = xr[r];

  // Prefetch DPP-level twiddles from LDS (land during in-lane levels).
  float wA[16], wB[16];
  loadw_A<5>(wA, lds_bw, lane);
  loadw_A<4>(wB, lds_bw, lane);

  // Layout A: levels 9..6 in-lane, 5 and 4 via DPP.
  level_inlane<9, true>(v, xr, bw, lw);
  level_inlane<8, true>(v, xr, bw, lw);
  level_inlane<7, true>(v, xr, bw, lw);
  level_inlane<6, true>(v, xr, bw, lw);
  level_dpp<5, true>(v, xr, wA, lw, lane);
  level_dpp<4, true>(v, xr, wB, lw, lane);

  // Read xr back in B layout BEFORE overwriting the buffer with v.
  float xrB[16];
#pragma unroll
  for (int r = 0; r < 16; ++r) xrB[r] = buf[swz(r*64 + lane)];

  // Transpose v: A -> B through the same buffer.
#pragma unroll
  for (int k = 0; k < 4; ++k) {
    float4 f;
    f.x = v[4*k+0]; f.y = v[4*k+1]; f.z = v[4*k+2]; f.w = v[4*k+3];
    *reinterpret_cast<float4*>(buf + swz(lane*16 + 4*k)) = f;
  }

  // B-twiddles for the first two B-levels ride the same DS queue.
  float w3[2], w2[4], w1[8], w0[16];
  loadw_B<3>(w3, lds_bw, lane);
  loadw_B<2>(w2, lds_bw, lane);

#pragma unroll
  for (int r = 0; r < 16; ++r) v[r] = buf[swz(r*64 + lane)];

  // Layout B: levels 3..0 all in-lane (pure VALU).
  level_B<3, true >(v, xrB, w3, lw);
  loadw_B<1>(w1, lds_bw, lane);
  level_B<2, true >(v, xrB, w2, lw);
  loadw_B<0>(w0, lds_bw, lane);
  level_B<1, false>(v, xrB, w1, lw);   // RES[1] = False
  level_B<0, true >(v, xrB, w0, lw);

  // Nontemporal coalesced stores (r22 win: out stops polluting caches).
#pragma unroll
  for (int r = 0; r < 16; ++r)
    __builtin_nontemporal_store(v[r], &out[base + r*64 + lane]);
}

extern "C" void kernel_launch(void* const* d_in, const int* in_sizes, int n_in,
                              void* d_out, int out_size, void* d_ws, size_t ws_size,
                              hipStream_t stream) {
  const float* x  = (const float*)d_in[0];
  const float* bw = (const float*)d_in[1];
  const float* lw = (const float*)d_in[2];
  float* out = (float*)d_out;
  const int nvec = in_sizes[0] / VECLEN;        // 16384 vectors
  const int wpb = 4;                            // waves per block (256 threads)
  const int blocks = (nvec + wpb - 1) / wpb;    // 4096, exact
  rnnfft_kernel<<<blocks, 256, 0, stream>>>(x, bw, lw, out, nvec);
}